// Round 1
// baseline (683.079 us; speedup 1.0000x reference)
//
#include <hip/hip_runtime.h>
#include <hip/hip_bf16.h>

#define BATCH 32
#define NPATCH 4096
#define DIM 768
#define HH 1024
#define WW 1024
#define KSEL 1024
#define SIDE 64

// ---------------------------------------------------------------------------
// Kernel A: center-of-gravity sums per batch, fp64 accumulation.
// sums[b*3+0] = sum(ld), sums[b*3+1] = sum(ld*y), sums[b*3+2] = sum(ld*x)
// y[h] = h * fl(1/1023) (endpoint forced to 1.0), matching np.linspace.
// ---------------------------------------------------------------------------
__global__ __launch_bounds__(256) void cog_kernel(const float* __restrict__ ld,
                                                  double* __restrict__ sums) {
    const int b   = blockIdx.x;   // batch
    const int blk = blockIdx.y;   // 32 blocks per batch
    const int tid = threadIdx.x;
    const float4* base = (const float4*)(ld + (size_t)b * (HH * WW));
    const double step = 1.0 / 1023.0;

    double m = 0.0, ys = 0.0, xs = 0.0;
    // per batch: 1M pixels = 262144 float4; 32 blocks -> 8192 f4/block; 256 thr -> 32/thr
    for (int it = 0; it < 32; ++it) {
        int v4 = blk * 8192 + it * 256 + tid;
        float4 v = base[v4];
        int p0 = v4 << 2;
        int h = p0 >> 10;
        int w = p0 & 1023;          // w % 4 == 0, so w..w+3 same row
        double y  = (h == 1023) ? 1.0 : h * step;
        double x0 = w * step;
        double x1 = (w + 1) * step;
        double x2 = (w + 2) * step;
        double x3 = (w + 3 == 1023) ? 1.0 : (w + 3) * step;
        double vx = (double)v.x, vy = (double)v.y, vz = (double)v.z, vw = (double)v.w;
        double srow = vx + vy + vz + vw;
        m  += srow;
        ys += y * srow;
        xs += x0 * vx + x1 * vy + x2 * vz + x3 * vw;
    }

    __shared__ double rm[256], ry[256], rx[256];
    rm[tid] = m; ry[tid] = ys; rx[tid] = xs;
    __syncthreads();
    for (int s = 128; s > 0; s >>= 1) {
        if (tid < s) { rm[tid] += rm[tid + s]; ry[tid] += ry[tid + s]; rx[tid] += rx[tid + s]; }
        __syncthreads();
    }
    if (tid == 0) {
        atomicAdd(&sums[b * 3 + 0], rm[0]);
        atomicAdd(&sums[b * 3 + 1], ry[0]);
        atomicAdd(&sums[b * 3 + 2], rx[0]);
    }
}

// ---------------------------------------------------------------------------
// Kernel B: per-batch weighted scores (fp64) + selection.
// One block (1024 threads) per batch. Full bitonic sort of 4096 (ws,idx)
// pairs, descending by ws, ties ascending by idx (stable-argsort semantics).
// Partial mode: above-threshold indices ascending (via prefix scan), then
// fill from sorted order.
// ---------------------------------------------------------------------------
__global__ __launch_bounds__(1024) void select_kernel(const float* __restrict__ scores,
                                                      const double* __restrict__ sums,
                                                      int* __restrict__ sel) {
    const int b = blockIdx.x;
    const int tid = threadIdx.x;

    __shared__ double ws[NPATCH];           // 32 KB
    __shared__ int    vals[NPATCH];         // 16 KB
    __shared__ unsigned short slot[NPATCH]; // 8 KB  (prefix | flag<<15)
    __shared__ int    waveTot[16];
    __shared__ int    cnt;

    double mass = sums[b * 3 + 0] + 1e-8;
    double cy   = sums[b * 3 + 1] / mass;
    double cx   = sums[b * 3 + 2] / mass;
    const double step = 1.0 / 63.0;

    // weighted scores in fp64, matching np float64 path
    for (int p = tid; p < NPATCH; p += 1024) {
        int r = p >> 6, c = p & 63;
        double gy = (r == 63) ? 1.0 : r * step;
        double gx = (c == 63) ? 1.0 : c * step;
        double dy = gy - cy, dx = gx - cx;
        double d2 = dy * dy + dx * dx;
        double g  = exp(d2 * -8.0);          // -d2/0.125, exact scaling
        ws[p]   = (double)scores[b * NPATCH + p] * g;
        vals[p] = p;
    }
    __syncthreads();

    // flags + exclusive prefix scan over index order (thread t owns [4t,4t+4))
    int f[4]; int sl = 0;
    #pragma unroll
    for (int i = 0; i < 4; ++i) { f[i] = (ws[tid * 4 + i] > 0.3) ? 1 : 0; sl += f[i]; }
    int lane = tid & 63, wave = tid >> 6;
    int inc = sl;
    #pragma unroll
    for (int off = 1; off < 64; off <<= 1) {
        int n = __shfl_up(inc, off);
        if (lane >= off) inc += n;
    }
    if (lane == 63) waveTot[wave] = inc;
    __syncthreads();
    int waveBase = 0;
    for (int i = 0; i < wave; ++i) waveBase += waveTot[i];
    int run = waveBase + inc - sl;   // exclusive prefix at this thread's first element
    #pragma unroll
    for (int i = 0; i < 4; ++i) {
        slot[tid * 4 + i] = (unsigned short)(run | (f[i] << 15));
        run += f[i];
    }
    if (tid == 1023) cnt = run;      // total above-threshold count

    // bitonic sort: final order = descending ws, ties ascending idx
    for (int size = 2; size <= NPATCH; size <<= 1) {
        for (int stride = size >> 1; stride > 0; stride >>= 1) {
            __syncthreads();
            #pragma unroll
            for (int ii = 0; ii < 4; ++ii) {
                int i = tid + ii * 1024;
                int j = i ^ stride;
                if (j > i) {
                    double wi = ws[i], wj = ws[j];
                    int vi = vals[i], vj = vals[j];
                    bool up = ((i & size) == 0);
                    bool doswap = up ? ((wj > wi) || (wj == wi && vj < vi))
                                     : ((wi > wj) || (wi == wj && vi < vj));
                    if (doswap) { ws[i] = wj; ws[j] = wi; vals[i] = vj; vals[j] = vi; }
                }
            }
        }
    }
    __syncthreads();

    const int count = cnt;
    int* selB = sel + b * KSEL;
    const bool partial = (count > 0 && count < KSEL);
    if (!partial) {
        selB[tid] = vals[tid];                       // top-k descending
    } else {
        if (tid >= count) selB[tid] = vals[tid];     // below-threshold fill, rank order
        #pragma unroll
        for (int i = 0; i < 4; ++i) {
            unsigned short sv = slot[tid * 4 + i];
            if (sv & 0x8000) selB[sv & 0x7FFF] = tid * 4 + i;  // above, ascending index
        }
    }
}

// ---------------------------------------------------------------------------
// Kernel C: gather + add. One block per output row (b,j), 192 threads,
// float4 per lane (3 KB contiguous per row -> fully coalesced).
// ---------------------------------------------------------------------------
__global__ __launch_bounds__(192) void gather_kernel(const float4* __restrict__ magno,
                                                     const float4* __restrict__ emb,
                                                     const int* __restrict__ sel,
                                                     float4* __restrict__ out) {
    const int r  = blockIdx.x;      // b*KSEL + j
    const int d4 = threadIdx.x;     // 0..191
    const int s  = sel[r];
    const int b  = r >> 10;
    float4 a = magno[(size_t)(b * NPATCH + s) * 192 + d4];
    float4 p = emb[(size_t)(1 + s) * 192 + d4];   // skip CLS row of (1,4097,768)
    float4 o;
    o.x = a.x + p.x; o.y = a.y + p.y; o.z = a.z + p.z; o.w = a.w + p.w;
    out[(size_t)r * 192 + d4] = o;
}

extern "C" void kernel_launch(void* const* d_in, const int* in_sizes, int n_in,
                              void* d_out, int out_size, void* d_ws, size_t ws_size,
                              hipStream_t stream) {
    const float* magno  = (const float*)d_in[0];   // (32,4096,768)
    const float* emb    = (const float*)d_in[1];   // (1,4097,768)
    const float* scores = (const float*)d_in[2];   // (32,4096)
    const float* ld     = (const float*)d_in[3];   // (32,1,1024,1024)
    float* out = (float*)d_out;                    // (32,1024,768)

    double* sums = (double*)d_ws;                  // 96 doubles (768 B)
    int* sel = (int*)((char*)d_ws + 1024);         // 32768 ints (128 KB)

    hipMemsetAsync(d_ws, 0, 768, stream);          // zero the atomic accumulators
    cog_kernel<<<dim3(BATCH, 32), 256, 0, stream>>>(ld, sums);
    select_kernel<<<BATCH, 1024, 0, stream>>>(scores, sums, sel);
    gather_kernel<<<BATCH * KSEL, 192, 0, stream>>>((const float4*)magno, (const float4*)emb,
                                                    sel, (float4*)out);
}